// Round 9
// baseline (95.063 us; speedup 1.0000x reference)
//
#include <hip/hip_runtime.h>
#include <hip/hip_bf16.h>

// NT-Xent (SimCLR) fused loss, MI355X gfx950. Round 17: MEASUREMENT round.
// r16 post-mortem: one-tile blocks regressed (+15us vs r14) -> persistent
// blocks (A-reuse, warm CU) win; tail theory dead. r14 (78.7us) is best,
// but its simclr (~31us) has NEVER appeared in the counter top-5 (fill =
// 42us dominates), and the busy-work model is off 4x for 6 rounds. This
// round: EXACT r14 structure, compute phase repeated REPS=2 (rep-opaque
// via asm touches on acc + opaque 0 offset on the load pointer, so loads/
// MFMAs can't be CSE'd -- guide rule #17); ALL atomics & pos stores only
// on the last rep (atomic cost NOT inflated). Bit-identical result;
// simclr ~2C+F ~55us -> top-5 - full counters for the real structure.
// Pre-committed reads: VALUBusy>50% -> epilogue VALU pig; MfmaUtil>35% ->
// MFMA off ubench; both low -> latency-bound -> slim tile for more waves.
//
// ws layout: [S: N f32][pos: N f32][znf: N*D fp8 frag-major]

#define N_TOT 8192
#define BATCH 4096
#define DIM   256                    // fp8 bytes per row
#define NT_TILES 64                  // 8192 / 128
#define REPS  2                      // measurement: double the compute phase
#define LOG2E_T 14.4269504089f       // 10 * log2(e)  (temperature folded)

typedef int   v8i32 __attribute__((ext_vector_type(8)));
typedef float f32x4 __attribute__((ext_vector_type(4)));

// znf layout: for 16-row group G (rows G*16+c, c=0..15), k-half h (0/1),
// quad q (0..3): 512-byte block at ((G*2+h)*4+q)*512. Lane c's 32 bytes
// (row G*16+c, row-bytes [16*(8h+2q), +32)) live contiguously at c*32.

// One wave per row: 64 lanes x float4 -> 4 fp8 bytes/lane, scattered into
// fragment-major znf. Also zeros S.
__global__ __launch_bounds__(256) void normalize_kernel(
    const float* __restrict__ z, unsigned char* __restrict__ znf,
    float* __restrict__ S) {
  const int wave = threadIdx.x >> 6;
  const int lane = threadIdx.x & 63;
  const int row  = blockIdx.x * 4 + wave;
  float4 v = ((const float4*)(z + (size_t)row * DIM))[lane];
  float ss = v.x * v.x + v.y * v.y + v.z * v.z + v.w * v.w;
#pragma unroll
  for (int m = 1; m <= 32; m <<= 1) ss += __shfl_xor(ss, m);
  float inv = 1.0f / sqrtf(ss);
  int p01 = __builtin_amdgcn_cvt_pk_fp8_f32(v.x * inv, v.y * inv, 0, false);
  int p23 = __builtin_amdgcn_cvt_pk_fp8_f32(v.z * inv, v.w * inv, 0, false);
  unsigned int packed =
      ((unsigned int)p01 & 0xffffu) | ((unsigned int)p23 << 16);
  const int G = row >> 4, c = row & 15;
  const int h = lane >> 5, q = (lane >> 3) & 3, lb = (lane >> 2) & 1;
  *(unsigned int*)(znf + (((size_t)(G * 2 + h) * 4 + q) << 9) + c * 32 +
                   lb * 16 + (lane & 3) * 4) = packed;
  if (threadIdx.x < 4) S[blockIdx.x * 4 + threadIdx.x] = 0.0f;
}

// Load one (row-group, k-half) fragment (32 B/lane) straight from L2.
__device__ __forceinline__ v8i32 load_frag_g(
    const unsigned char* __restrict__ znf, int G, int h, int quad, int c) {
  const int4* p =
      (const int4*)(znf + (((size_t)(G * 2 + h) * 4 + quad) << 9) + c * 32);
  int4 lo = p[0];
  int4 hi = p[1];
  return (v8i32){lo.x, lo.y, lo.z, lo.w, hi.x, hi.y, hi.z, hi.w};
}

// Tile epilogue: register-only. MODE 0 = plain, 1 = diagonal (mask
// self-sim; caller skips col flush -- symmetric, rows cover), 2 = partner
// (jj==32: emit pos logits, only when `last`).
template <int MODE>
__device__ __forceinline__ void epilogue_tile(
    const f32x4 (&acc)[4][4], float (&rs)[16], float (&cs)[4],
    float* __restrict__ pos, int rb, int cbt, int wm, int wn, int c,
    int quad, bool last) {
#pragma unroll
  for (int fm = 0; fm < 4; ++fm) {
#pragma unroll
    for (int r = 0; r < 4; ++r) {
      const int grow = rb * 128 + wm * 64 + fm * 16 + quad * 4 + r;
#pragma unroll
      for (int fn = 0; fn < 4; ++fn) {
        const int gcol = cbt * 128 + wn * 64 + fn * 16 + c;
        // exp(acc*10) == exp2(acc * 10*log2(e)); raw v_exp_f32, no libcall
        float e = __builtin_amdgcn_exp2f(acc[fm][fn][r] * LOG2E_T);
        if (MODE == 1 && gcol == grow) e = 0.f;   // exclude self-similarity
        if (MODE == 2 && last && ((gcol ^ grow) == BATCH)) {
          const float logit = acc[fm][fn][r] * 10.0f;
          pos[grow] = logit;                       // unique writer/elem
          pos[gcol] = logit;                       // sim symmetric
        }
        rs[fm * 4 + r] += e;
        cs[fn] += e;
      }
    }
  }
}

__global__ __launch_bounds__(256, 2) void simclr_tile_kernel(
    const unsigned char* __restrict__ znf, float* __restrict__ S,
    float* __restrict__ pos) {
  const int g = blockIdx.x;                    // j-group 0..7
  const int rb = blockIdx.y;                   // row band 0..63 (A, fixed)
  const int tid = threadIdx.x;
  const int wave = tid >> 6, lane = tid & 63;
  const int wm = wave >> 1, wn = wave & 1;     // wave quadrant (2x2)
  const int c = lane & 15, quad = lane >> 4;   // MFMA lane coords

  const int ntile = (g == 0 && rb < 32) ? 5 : 4;  // g0 also does j=32

  // A-fragments -> registers once per block, straight from L2.
  v8i32 af[4][2];
#pragma unroll
  for (int f = 0; f < 4; ++f)
#pragma unroll
    for (int h = 0; h < 2; ++h)
      af[f][h] = load_frag_g(znf, rb * 8 + wm * 4 + f, h, quad, c);

  for (int rep = 0; rep < REPS; ++rep) {
    const bool last = (rep == REPS - 1);
    // Opaque zero: compiler cannot prove reps load the same bytes -> no CSE
    // of the B loads across reps. Value is 0, so results are identical.
    int off = 0;
    asm volatile("" : "+v"(off));
    const unsigned char* zr = znf + off;

    float rs[16];
#pragma unroll
    for (int i = 0; i < 16; ++i) rs[i] = 0.f;

    for (int t = 0; t < ntile; ++t) {
      const int jj = (t == 4) ? 32 : (g * 4 + t);
      const int cbt = (rb + jj) & 63;

      v8i32 bf[4][2];
#pragma unroll
      for (int f = 0; f < 4; ++f)
#pragma unroll
        for (int h = 0; h < 2; ++h)
          bf[f][h] = load_frag_g(zr, cbt * 8 + wn * 4 + f, h, quad, c);

      f32x4 acc[4][4];
#pragma unroll
      for (int i = 0; i < 4; ++i)
#pragma unroll
        for (int k = 0; k < 4; ++k) {
          acc[i][k] = (f32x4){0.f, 0.f, 0.f, 0.f};
          asm volatile("" : "+v"(acc[i][k]));  // opaque -> MFMAs not folded
        }

#pragma unroll
      for (int h = 0; h < 2; ++h)
#pragma unroll
        for (int fm = 0; fm < 4; ++fm)
#pragma unroll
          for (int fn = 0; fn < 4; ++fn)
            acc[fm][fn] = __builtin_amdgcn_mfma_scale_f32_16x16x128_f8f6f4(
                af[fm][h], bf[fn][h], acc[fm][fn],
                0, 0,                 // cbsz = fp8(A), blgp = fp8(B)
                0, 0x7f,              // opsel_a, scale_a = E8M0 1.0
                0, 0x7f);             // opsel_b, scale_b = E8M0 1.0

      float cs[4] = {0.f, 0.f, 0.f, 0.f};
      if (g == 0 && t == 0)
        epilogue_tile<1>(acc, rs, cs, pos, rb, cbt, wm, wn, c, quad, last);
      else if (t == 4)
        epilogue_tile<2>(acc, rs, cs, pos, rb, cbt, wm, wn, c, quad, last);
      else
        epilogue_tile<0>(acc, rs, cs, pos, rb, cbt, wm, wn, c, quad, last);

      // Column sums (transpose contribution); diag tile skipped. Flushed
      // only on the last rep -> atomic count identical to the r14 kernel.
      if (last && !(g == 0 && t == 0)) {
#pragma unroll
        for (int fn = 0; fn < 4; ++fn) {
          float v = cs[fn];
          v += __shfl_xor(v, 16);
          v += __shfl_xor(v, 32);
          if (quad == 0)
            atomicAdd(&S[cbt * 128 + wn * 64 + fn * 16 + c], v);
        }
      }
    }

    if (last) {
      // Row sums: shuffle-reduce + one atomic per row.
#pragma unroll
      for (int fm = 0; fm < 4; ++fm) {
#pragma unroll
        for (int r = 0; r < 4; ++r) {
          float s = rs[fm * 4 + r];
          s += __shfl_xor(s, 1);
          s += __shfl_xor(s, 2);
          s += __shfl_xor(s, 4);
          s += __shfl_xor(s, 8);
          if (c == 0) {
            const int grow = rb * 128 + wm * 64 + fm * 16 + quad * 4 + r;
            atomicAdd(&S[grow], s);
          }
        }
      }
    }
  }
}

// loss = mean(log(S_i) - pos_i); single block (cheap, ~2us).
__global__ __launch_bounds__(1024) void finalize_kernel(
    const float* __restrict__ S, const float* __restrict__ pos,
    float* __restrict__ out) {
  const int tid = threadIdx.x;
  float a = 0.f;
  for (int i = tid; i < N_TOT; i += 1024) a += __logf(S[i]) - pos[i];
#pragma unroll
  for (int m = 1; m <= 32; m <<= 1) a += __shfl_xor(a, m);
  __shared__ float red[16];
  if ((tid & 63) == 0) red[tid >> 6] = a;
  __syncthreads();
  if (tid < 16) {
    float v = red[tid];
    v += __shfl_xor(v, 1);
    v += __shfl_xor(v, 2);
    v += __shfl_xor(v, 4);
    v += __shfl_xor(v, 8);
    if (tid == 0) out[0] = v * (1.0f / (float)N_TOT);
  }
}

extern "C" void kernel_launch(void* const* d_in, const int* in_sizes, int n_in,
                              void* d_out, int out_size, void* d_ws,
                              size_t ws_size, hipStream_t stream) {
  const float* z = (const float*)d_in[0];
  float* out = (float*)d_out;
  char* ws = (char*)d_ws;
  float* S = (float*)ws;                                   // N floats
  float* pos = (float*)(ws + N_TOT * sizeof(float));       // N floats
  unsigned char* znf =
      (unsigned char*)(ws + 2 * N_TOT * sizeof(float));    // N*D fp8

  normalize_kernel<<<N_TOT / 4, 256, 0, stream>>>(z, znf, S);
  dim3 grid(8, NT_TILES);
  simclr_tile_kernel<<<grid, 256, 0, stream>>>(znf, S, pos);
  finalize_kernel<<<1, 1024, 0, stream>>>(S, pos, out);
}